// Round 1
// baseline (1560.521 us; speedup 1.0000x reference)
//
#include <hip/hip_runtime.h>

// SimpleRNN: B=4096, K=512, U=3, P=5, H=128, L=32, N_SUB=10
// 256 blocks x 512 threads; 16 batch rows per block (1 block/CU).
// GEMMs via mfma_f32_16x16x32_bf16; weights pre-packed into VGPR B-fragments.
// Wave 7 owns head+theta+RK4 (the serial pole); other waves issue next-step gh.

#define KSTEPS 512
#define NTHREADS 512

typedef short s16x8 __attribute__((ext_vector_type(8)));
typedef float f32x4 __attribute__((ext_vector_type(4)));

__device__ __forceinline__ unsigned short f2bf(float f) {
  union { float f; unsigned u; } v; v.f = f;
  unsigned r = v.u + 0x7FFFu + ((v.u >> 16) & 1u);  // RNE
  return (unsigned short)(r >> 16);
}

__device__ __forceinline__ float ex2(float x) {
#if __has_builtin(__builtin_amdgcn_exp2f)
  return __builtin_amdgcn_exp2f(x);
#else
  return exp2f(x);
#endif
}
__device__ __forceinline__ float rcp_(float x) {
#if __has_builtin(__builtin_amdgcn_rcpf)
  return __builtin_amdgcn_rcpf(x);
#else
  return 1.0f / x;
#endif
}
__device__ __forceinline__ float sigm(float x) {
  return rcp_(1.0f + ex2(-1.44269504088896f * x));
}
__device__ __forceinline__ float tanh_(float x) {
  return fmaf(2.0f, rcp_(1.0f + ex2(-2.88539008177793f * x)), -1.0f);
}
__device__ __forceinline__ f32x4 splat4(float v) { f32x4 r = {v, v, v, v}; return r; }

__device__ __forceinline__ f32x4 MFMA(s16x8 a, s16x8 b, f32x4 c) {
  return __builtin_amdgcn_mfma_f32_16x16x32_bf16(a, b, c, 0, 0, 0);
}

// pack 8 consecutive fp32 -> one bf16 B/A fragment register group
__device__ __forceinline__ s16x8 bfrag_g(const float* __restrict__ src8) {
  s16x8 r;
#pragma unroll
  for (int j = 0; j < 8; ++j) r[j] = (short)f2bf(src8[j]);
  return r;
}

__global__ __launch_bounds__(NTHREADS, 2) void rnn_scan_kernel(
    const float* __restrict__ y0, const float* __restrict__ u_seq,
    const float* __restrict__ dt_seq, const float* __restrict__ lift_W,
    const float* __restrict__ lift_b, const float* __restrict__ W_ih,
    const float* __restrict__ W_hh, const float* __restrict__ b_ih,
    const float* __restrict__ b_hh, const float* __restrict__ head_W,
    const float* __restrict__ head_b, const float* __restrict__ jumpW,
    float* __restrict__ y_out, float* __restrict__ th_out) {
  // A-fragment interchange buffers (16B-aligned for ds_read_b128)
  __shared__ __align__(16) unsigned short s_Ah[2048];  // h (K=128): 4 ksteps x 512
  __shared__ __align__(16) unsigned short s_Ax[512];   // x (K=32)
  __shared__ __align__(16) unsigned short s_Af[512];   // feat (K=8, zero-padded to 32)
  __shared__ float s_theta[128];  // 16 rows x 8
  __shared__ float s_y[80];       // 16 rows x 5 (fp32 state)
  __shared__ float s_u2[2][384];  // 8-step u chunks: row*24 + kb*3 + c
  __shared__ float s_dt2[2][128]; // 8-step dt chunks: row*8 + kb
  __shared__ float s_jump[16];

  const int tid = threadIdx.x;
  const int w = tid >> 6;       // wave 0..7
  const int lane = tid & 63;
  const int quad = lane >> 4;
  const int col = lane & 15;
  const int r0 = blockIdx.x << 4;  // 16 rows per block

  // ---- one-time: B fragments into registers (B[k][n]: n=lane&15, k=quad*8+j) ----
  // wave w owns output columns 16w (r), 128+16w (z), 256+16w (n)
  s16x8 bih_r = bfrag_g(&W_ih[((w)*16 + col) * 32 + quad * 8]);
  s16x8 bih_z = bfrag_g(&W_ih[((8 + w) * 16 + col) * 32 + quad * 8]);
  s16x8 bih_n = bfrag_g(&W_ih[((16 + w) * 16 + col) * 32 + quad * 8]);
  s16x8 bhh_r[4], bhh_z[4], bhh_n[4], bhd[4];
#pragma unroll
  for (int s = 0; s < 4; ++s) {
    bhh_r[s] = bfrag_g(&W_hh[((w)*16 + col) * 128 + s * 32 + quad * 8]);
    bhh_z[s] = bfrag_g(&W_hh[((8 + w) * 16 + col) * 128 + s * 32 + quad * 8]);
    bhh_n[s] = bfrag_g(&W_hh[((16 + w) * 16 + col) * 128 + s * 32 + quad * 8]);
    if (col < 8) {
      bhd[s] = bfrag_g(&head_W[col * 128 + s * 32 + quad * 8]);
    } else {
      s16x8 z = {0, 0, 0, 0, 0, 0, 0, 0};
      bhd[s] = z;
    }
  }
  s16x8 blft;
  if (quad == 0) {  // lift K=8: only k<8 nonzero
    blft = bfrag_g(&lift_W[((w & 1) * 16 + col) * 8]);
  } else {
    s16x8 z = {0, 0, 0, 0, 0, 0, 0, 0};
    blft = z;
  }
  const float brz_r = b_ih[w * 16 + col] + b_hh[w * 16 + col];
  const float brz_z = b_ih[128 + w * 16 + col] + b_hh[128 + w * 16 + col];
  const float bn_i = b_ih[256 + w * 16 + col];
  const float bn_h = b_hh[256 + w * 16 + col];
  const float lb = lift_b[(w & 1) * 16 + col];
  const float hb = (col < 8) ? head_b[col] : 0.0f;

  // ---- one-time LDS init ----
  for (int i = tid; i < 512; i += NTHREADS) s_Af[i] = 0;  // quads 1..3 stay zero
  if (tid < 16) s_jump[tid] = (tid < 15) ? jumpW[tid] : 0.0f;
  if (tid < 80) {
    int row = tid / 5, c = tid % 5;
    s_y[tid] = y0[(r0 + row) * 5 + c] + 0.01f;
  }
  if (tid < 384) {  // u chunk for steps 0..7
    int row = tid / 24, off = tid % 24;
    s_u2[0][tid] = u_seq[((size_t)(r0 + row) * KSTEPS) * 3 + off];
  }
  if (tid < 128) {  // dt chunk for steps 0..7
    int row = tid >> 3, kk = tid & 7;
    s_dt2[0][tid] = dt_seq[(size_t)(r0 + row) * KSTEPS + kk];
  }
  __syncthreads();

  // h-column this lane produces (C-layout col) -> A-fragment scatter offset
  const int kkh = w * 16 + col;  // 0..127
  const int hoff = ((kkh >> 5) << 9) + (((kkh >> 3) & 3) << 7) + (kkh & 7);
  const int xoff = (((kkh & 31) >> 3) << 7) + (kkh & 7);  // valid for w<2

  f32x4 ar = splat4(brz_r);   // r preact: b_ih+b_hh (+gh from prev iter)
  f32x4 az = splat4(brz_z);   // z preact
  f32x4 angi = splat4(bn_i);  // n: gi part (b_ih_n + x@Wih_n)
  f32x4 angh = splat4(bn_h);  // n: gh part (b_hh_n + h@Whh_n)
  float h_reg[4] = {0.f, 0.f, 0.f, 0.f};  // h0 = 0

#pragma unroll 1
  for (int k = 0; k < KSTEPS; ++k) {
    const int kb = k & 7;
    const int cb = (k >> 3) & 1;
    __syncthreads();  // T: y_{k-1} final, u-chunk ready
    if (tid < 16) {   // feat = [u_k, y_prev] -> A-frag quad 0 (k<8)
      const float* ur = &s_u2[cb][tid * 24 + kb * 3];
      const float* yr = &s_y[tid * 5];
      unsigned short* dst = &s_Af[tid * 8];
      dst[0] = f2bf(ur[0]); dst[1] = f2bf(ur[1]); dst[2] = f2bf(ur[2]);
      dst[3] = f2bf(yr[0]); dst[4] = f2bf(yr[1]); dst[5] = f2bf(yr[2]);
      dst[6] = f2bf(yr[3]); dst[7] = f2bf(yr[4]);
    }
    __syncthreads();  // B1: feat ready
    if (w < 2) {      // lift: x = silu(feat @ lift_W^T + b), N-tile w
      f32x4 ax = splat4(lb);
      ax = MFMA(*(const s16x8*)&s_Af[lane * 8], blft, ax);
#pragma unroll
      for (int i = 0; i < 4; ++i) {
        float v = ax[i];
        float xs = v * sigm(v);
        s_Ax[xoff + ((quad << 2) + i) * 8] = f2bf(xs);
      }
    }
    __syncthreads();  // B2: x ready
    {                 // gi MFMAs complete the gate preactivations
      s16x8 axf = *(const s16x8*)&s_Ax[lane * 8];
      ar = MFMA(axf, bih_r, ar);
      az = MFMA(axf, bih_z, az);
      angi = MFMA(axf, bih_n, angi);
    }
#pragma unroll
    for (int i = 0; i < 4; ++i) {  // gates + h update (fp32)
      float r = sigm(ar[i]);
      float z = sigm(az[i]);
      float n = tanh_(fmaf(r, angh[i], angi[i]));
      float hn = fmaf(z, h_reg[i] - n, n);  // (1-z)n + z h
      h_reg[i] = hn;
      s_Ah[hoff + ((quad << 2) + i) * 8] = f2bf(hn);
    }
    __syncthreads();  // B3: h_k A-fragments ready

    // reset accumulators with biases for step k+1
    ar = splat4(brz_r);
    az = splat4(brz_z);
    angi = splat4(bn_i);
    angh = splat4(bn_h);
    s16x8 ah[4];
#pragma unroll
    for (int s = 0; s < 4; ++s) ah[s] = *(const s16x8*)&s_Ah[(s << 9) + lane * 8];

    if (w == 7) {
      // ---- head -> theta -> RK4 on the critical wave (no extra barrier:
      //      theta exchange is same-wave LDS, ordered by the DS pipe) ----
      f32x4 ahd = splat4(hb);
#pragma unroll
      for (int s = 0; s < 4; ++s) ahd = MFMA(ah[s], bhd[s], ahd);
      if (col < 8) {
#pragma unroll
        for (int i = 0; i < 4; ++i) {
          int row = (quad << 2) + i;
          float th = fmaf(2.99f, sigm(ahd[i]), 0.01f);
          s_theta[row * 8 + col] = th;
          th_out[((size_t)(r0 + row) * KSTEPS + k) * 8 + col] = th;
        }
      }
      if (lane < 16) {  // one lane per batch row
        const int row = lane;
        float th[8];
#pragma unroll
        for (int i = 0; i < 8; ++i) th[i] = s_theta[row * 8 + i];
        float y[5];
#pragma unroll
        for (int i = 0; i < 5; ++i) y[i] = s_y[row * 5 + i];
        const float* ur = &s_u2[cb][row * 24 + kb * 3];
        float u0v = ur[0], u1v = ur[1], u2v = ur[2];
#pragma unroll
        for (int i = 0; i < 5; ++i)
          y[i] += u0v * s_jump[i] + u1v * s_jump[5 + i] + u2v * s_jump[10 + i];
        float hs = s_dt2[cb][row * 8 + kb] * 0.1f;
        float hs2 = hs * 0.5f, hs6 = hs * (1.0f / 6.0f);
        auto RHS = [&th](const float* yy, float* dd) {
          float f1 = fmaf(th[0], yy[0], -th[4] * yy[1]);
          float f2 = fmaf(th[1], yy[1], -th[5] * yy[2]);
          float f3 = fmaf(th[2], yy[2], -th[6] * yy[3]);
          float f4 = fmaf(th[3], yy[3], -th[7] * yy[4]);
          dd[0] = -f1; dd[1] = f1 - f2; dd[2] = f2 - f3;
          dd[3] = f3 - f4; dd[4] = f4;
        };
#pragma unroll 1
        for (int ss = 0; ss < 10; ++ss) {
          float k1[5], k2[5], k3[5], k4[5], t[5];
          RHS(y, k1);
#pragma unroll
          for (int i = 0; i < 5; ++i) t[i] = fmaf(hs2, k1[i], y[i]);
          RHS(t, k2);
#pragma unroll
          for (int i = 0; i < 5; ++i) t[i] = fmaf(hs2, k2[i], y[i]);
          RHS(t, k3);
#pragma unroll
          for (int i = 0; i < 5; ++i) t[i] = fmaf(hs, k3[i], y[i]);
          RHS(t, k4);
#pragma unroll
          for (int i = 0; i < 5; ++i) {
            float s2 = k2[i] + k3[i];
            float acc = fmaf(2.0f, s2, k1[i]) + k4[i];
            y[i] = fmaxf(fmaf(hs6, acc, y[i]), 0.0f);
          }
        }
        float* yo = y_out + ((size_t)(r0 + row) * KSTEPS + k) * 5;
#pragma unroll
        for (int i = 0; i < 5; ++i) {
          s_y[row * 5 + i] = y[i];
          yo[i] = y[i];
        }
      }
    }

    // gh for step k+1 (waves 0-6 run this while wave 7 is in RK4;
    // wave 7 issues its own after RK4 when the matrix pipe is free)
#pragma unroll
    for (int s = 0; s < 4; ++s) {
      ar = MFMA(ah[s], bhh_r[s], ar);
      az = MFMA(ah[s], bhh_z[s], az);
      angh = MFMA(ah[s], bhh_n[s], angh);
    }

    // prefetch next 8-step u/dt chunk (waves 1-2; hidden behind wave 7's RK4)
    if (kb == 0) {
      int kc = k + 8;
      if (kc > KSTEPS - 8) kc = KSTEPS - 8;
      const int nb = cb ^ 1;
      if (tid >= 64 && tid < 448) {
        int i = tid - 64, row = i / 24, off = i % 24;
        s_u2[nb][i] = u_seq[((size_t)(r0 + row) * KSTEPS + kc) * 3 + off];
      }
      if (tid >= 64 && tid < 192) {
        int i = tid - 64, row = i >> 3, kkk = i & 7;
        s_dt2[nb][i] = dt_seq[(size_t)(r0 + row) * KSTEPS + kc + kkk];
      }
    }
  }
}

extern "C" void kernel_launch(void* const* d_in, const int* in_sizes, int n_in,
                              void* d_out, int out_size, void* d_ws, size_t ws_size,
                              hipStream_t stream) {
  const float* y0 = (const float*)d_in[0];
  const float* u_seq = (const float*)d_in[1];
  const float* dt_seq = (const float*)d_in[2];
  const float* lift_W = (const float*)d_in[3];
  const float* lift_b = (const float*)d_in[4];
  const float* W_ih = (const float*)d_in[5];
  const float* W_hh = (const float*)d_in[6];
  const float* b_ih = (const float*)d_in[7];
  const float* b_hh = (const float*)d_in[8];
  const float* head_W = (const float*)d_in[9];
  const float* head_b = (const float*)d_in[10];
  const float* jumpW = (const float*)d_in[11];

  float* y_out = (float*)d_out;                          // (4096, 512, 5)
  float* th_out = y_out + (size_t)4096 * 512 * 5;        // (4096, 512, 8)

  rnn_scan_kernel<<<dim3(256), dim3(NTHREADS), 0, stream>>>(
      y0, u_seq, dt_seq, lift_W, lift_b, W_ih, W_hh, b_ih, b_hh, head_W,
      head_b, jumpW, y_out, th_out);
}